// Round 22
// baseline (5988.081 us; speedup 1.0000x reference)
//
#include <hip/hip_runtime.h>

#define B_    128
#define TPAST 1024
#define FN    512
#define TT    1536
#define INF   64
#define IPF   128
#define HD    256
#define NG    1024
#define OUTF  64

typedef _Float16 f16;
typedef _Float16 f16x8 __attribute__((ext_vector_type(8)));
typedef _Float16 f16x4 __attribute__((ext_vector_type(4)));
typedef float    f32x4 __attribute__((ext_vector_type(4)));

template<int N> struct ic { static constexpr int value = N; };

__device__ __forceinline__ float sigm_(float x) {
  return __builtin_amdgcn_rcpf(1.f + __expf(-x));
}
__device__ __forceinline__ float tanh_(float x) {
  return 1.f - 2.f * __builtin_amdgcn_rcpf(1.f + __expf(2.f * x));
}
// Opaque 16B load (asm result can't be rematerialized -> stays resident).
__device__ __forceinline__ f16x8 oload16(const f16* p) {
  f16x8 v;
  asm volatile("global_load_dwordx4 %0, %1, off\n\ts_waitcnt vmcnt(0)"
               : "=v"(v) : "v"(p));
  return v;
}
// Spin on a partner flag with RELAXED loads only. NO acquire fence: the
// agent-acquire fence invalidates the whole XCD L2 every step (r17/r18/r20
// triple-confirmed: FETCH 19->85MB). Data coherence is instead obtained by
// reading Hx itself through the coherence point (relaxed agent atomic
// loads, aload16 below) — correct for any WG->XCD placement (G16), no
// cache-wipe side effect.
__device__ __forceinline__ void spin_flag(const unsigned int* f, unsigned tgt) {
  while (__hip_atomic_load(f, __ATOMIC_RELAXED, __HIP_MEMORY_SCOPE_AGENT) < tgt)
    __builtin_amdgcn_s_sleep(1);
}
// Coherence-point 16B read as two relaxed agent-scope 8B atomic loads.
__device__ __forceinline__ f16x8 aload16(const f16* p) {
  union { unsigned long long u[2]; f16x8 v; } t;
  t.u[0] = __hip_atomic_load((const unsigned long long*)p,
                             __ATOMIC_RELAXED, __HIP_MEMORY_SCOPE_AGENT);
  t.u[1] = __hip_atomic_load((const unsigned long long*)(p + 4),
                             __ATOMIC_RELAXED, __HIP_MEMORY_SCOPE_AGENT);
  return t.v;
}

// ---------------------------------------------------------------------------
// prep (unchanged): fold encoder into past-input weights; fold future encoder
// into the future recurrent matrix; f16 weights.
// ---------------------------------------------------------------------------
extern "C" __global__ void eprep(
    const float* __restrict__ enc_W, const float* __restrict__ enc_b,
    const float* __restrict__ fut_W, const float* __restrict__ fut_b,
    const float* __restrict__ dec_W,
    const float* __restrict__ pW_ih, const float* __restrict__ pW_hh,
    const float* __restrict__ pb_ih, const float* __restrict__ pb_hh,
    const float* __restrict__ fW_ih, const float* __restrict__ fW_hh,
    const float* __restrict__ fb_ih, const float* __restrict__ fb_hh,
    f16* __restrict__ Wp_in, float* __restrict__ bp,
    f16* __restrict__ Wp16, f16* __restrict__ Wf16,
    float* __restrict__ bf, f16* __restrict__ dW16)
{
  int stride = gridDim.x * blockDim.x;
  int gid = blockIdx.x * blockDim.x + threadIdx.x;
  for (int i = gid; i < NG * HD; i += stride) {
    int n = i >> 8, j = i & 255;
    float s = fW_hh[i];
    for (int m = 0; m < IPF; ++m) s += fW_ih[n * IPF + m] * fut_W[m * HD + j];
    Wf16[i] = (f16)s;
    Wp16[i] = (f16)pW_hh[i];
  }
  for (int i = gid; i < NG * INF; i += stride) {
    int n = i >> 6, k = i & 63;
    float s = 0.f;
    for (int m = 0; m < IPF; ++m) s += pW_ih[n * IPF + m] * enc_W[m * INF + k];
    Wp_in[i] = (f16)s;
  }
  for (int i = gid; i < OUTF * HD; i += stride) dW16[i] = (f16)dec_W[i];
  for (int n = gid; n < NG; n += stride) {
    float s1 = pb_ih[n] + pb_hh[n], s2 = fb_ih[n] + fb_hh[n];
    for (int m = 0; m < IPF; ++m) {
      s1 += pW_ih[n * IPF + m] * enc_b[m];
      s2 += fW_ih[n * IPF + m] * fut_b[m];
    }
    bp[n] = s1; bf[n] = s2;
  }
}

// ---------------------------------------------------------------------------
// P GEMM, fragment-ordered "Q" layout (r14/r16, refcheck-passed, plain
// cached stores).
// ---------------------------------------------------------------------------
extern "C" __global__ __launch_bounds__(64) void epgemm(
    const float* __restrict__ x, const f16* __restrict__ Wp_in,
    const float* __restrict__ bp, f16* __restrict__ P, int t0, int Tc)
{
  int wg = blockIdx.x;
  int tl = wg >> 3, bt = wg & 7;
  int t = t0 + tl;
  int l = (int)threadIdx.x, r = l & 15, g = l >> 4;
  const float* xb = x + ((size_t)(bt * 16 + r) * TPAST + t) * INF;
  f16x8 a[2];
#pragma unroll
  for (int kk = 0; kk < 2; ++kk) {
    const float* px = xb + kk * 32 + g * 8;
    f32x4 v0 = *(const f32x4*)px;
    f32x4 v1 = *(const f32x4*)(px + 4);
#pragma unroll
    for (int e = 0; e < 4; ++e) { a[kk][e] = (f16)v0[e]; a[kk][4 + e] = (f16)v1[e]; }
  }
  for (int nt = 0; nt < 64; ++nt) {
    int n = nt * 16 + r;
    f16x8 w0 = *(const f16x8*)(Wp_in + (size_t)n * INF + g * 8);
    f16x8 w1 = *(const f16x8*)(Wp_in + (size_t)n * INF + 32 + g * 8);
    f32x4 acc = {0.f, 0.f, 0.f, 0.f};
    acc = __builtin_amdgcn_mfma_f32_16x16x32_f16(w0, a[0], acc, 0, 0, 0);
    acc = __builtin_amdgcn_mfma_f32_16x16x32_f16(w1, a[1], acc, 0, 0, 0);
    f32x4 bias4 = *(const f32x4*)&bp[nt * 16 + 4 * g];
    f16x4 hv;
#pragma unroll
    for (int e = 0; e < 4; ++e) hv[e] = (f16)(acc[e] + bias4[e]);
    int ga = nt >> 4, jhp = (nt >> 3) & 1, wc = (nt >> 1) & 3, sc = nt & 1;
    f16* Pt = P + ((size_t)(jhp * 8 + bt) * Tc + tl) * 8192;
    *(f16x4*)(Pt + ((ga * 8 + sc * 4 + wc) * 64 + l) * 4) = hv;
  }
}

// ---------------------------------------------------------------------------
// Persistent recurrent kernel: r21 base (best measured, 5.66 ms) with ONE
// isolated change — the per-step acquire fence is deleted and the partner
// Hx read goes through relaxed agent-scope atomic loads (coherence-point
// reads, no L2 invalidation). Ordering: producer's RELEASE flag orders its
// Hx stores at the coherence point; consumer observes flag (CP-routed) then
// control-dependently issues CP-routed data loads.
// ---------------------------------------------------------------------------
extern "C" __global__ __launch_bounds__(256, 1)
void erecur(
    const f16* __restrict__ W, const f16* __restrict__ P, int pstep,
    const float* __restrict__ bias,
    const f16* __restrict__ dW, const float* __restrict__ dec_b,
    float* __restrict__ out,
    f16* __restrict__ h_state, float* __restrict__ c_state,
    f16* __restrict__ Hx, unsigned int* __restrict__ flags,
    int Tc, int seq0, int init_state, int do_tail)
{
  __shared__ f16  Wl[512 * 96];     //  96 KB : W rows (this WG), cols 160..255
  __shared__ f16  Wd[32 * 256];     //  16 KB : decoder rows jh*32..+32, swizzled
  __shared__ f16  hb[3][16 * 128];  //  12 KB : own h half, TRI-buffered, swizzled
  __shared__ float cb[128 * 20];    //  10 KB : own c [jl][b], stride 20
  __shared__ f16  bl[512];          //   1 KB : future bias (own rows)

  int tid = (int)threadIdx.x;
  int w = tid >> 6, l = tid & 63, r = l & 15, g = l >> 4;
  int wg = blockIdx.x;
  int bs = wg & 7, jh = wg >> 3;
  int b0 = bs * 16;
  int pwg = wg ^ 8;

  for (int nl = tid; nl < 512; nl += 256) {
    int ng = (nl >> 7) * 256 + jh * 128 + (nl & 127);
#pragma unroll
    for (int c8 = 0; c8 < 12; ++c8) {
      f16x8 v = *(const f16x8*)(W + (size_t)ng * HD + 160 + c8 * 8);
      *(f16x8*)&Wl[(nl * 96 + c8 * 8) ^ ((nl & 7) << 3)] = v;
    }
  }
  // Decoder weight slice for this jh (rows jh*32 .. jh*32+32), swizzled
  for (int i = tid; i < 32 * 32; i += 256) {
    int row = i >> 5, c8 = i & 31;
    f16x8 v = *(const f16x8*)(dW + (size_t)(jh * 32 + row) * HD + c8 * 8);
    *(f16x8*)&Wd[(row * 256 + c8 * 8) ^ ((row & 7) << 3)] = v;
  }
  if (bias) {
    for (int i = tid; i < 512; i += 256) {
      int ng = (i >> 7) * 256 + jh * 128 + (i & 127);
      bl[i] = (f16)bias[ng];
    }
  }
  f16x8 wf[4][2][5];
#pragma unroll
  for (int ga = 0; ga < 4; ++ga)
#pragma unroll
    for (int s = 0; s < 2; ++s) {
      int ng = ga * 256 + jh * 128 + w * 32 + s * 16 + r;
#pragma unroll
      for (int kt = 0; kt < 5; ++kt)
        wf[ga][s][kt] = oload16(W + (size_t)ng * HD + kt * 32 + g * 8);
    }
  f32x4 dbias = *(const f32x4*)(dec_b + jh * 32 + (w & 1) * 16 + 4 * g);
  int o32 = (w & 1) * 16 + r;

  int cur3 = seq0 % 3;
  f16x8 pa[4];
  if (init_state) {
    for (int i = tid; i < 16 * 128; i += 256) {
      int b = i >> 7, jl = i & 127;
      hb[cur3][(b * 128 + jl) ^ ((b & 7) << 3)] = (f16)0.f;
    }
    for (int i = tid; i < 128 * 20; i += 256) cb[i] = 0.f;
    f16x8 z = {};
#pragma unroll
    for (int kt = 0; kt < 4; ++kt) pa[kt] = z;
  } else {
    for (int i = tid; i < 16 * 128; i += 256) {
      int b = i >> 7, jl = i & 127;
      hb[cur3][(b * 128 + jl) ^ ((b & 7) << 3)] =
          h_state[(size_t)(b0 + b) * HD + jh * 128 + jl];
    }
    for (int i = tid; i < 16 * 128; i += 256) {
      int b = i >> 7, jl = i & 127;
      cb[jl * 20 + b] = c_state[(size_t)(b0 + b) * HD + jh * 128 + jl];
    }
#pragma unroll
    for (int kt = 0; kt < 4; ++kt)
      pa[kt] = *(const f16x8*)(h_state + (size_t)(b0 + r) * HD + (jh ^ 1) * 128 + kt * 32 + g * 8);
  }
  const f16* Pw = P ? (P + (size_t)wg * Tc * pstep) : nullptr;
  __syncthreads();

  for (int tl = 0; tl < Tc; ++tl) {
    int v = seq0 + tl;
    int nxt3 = (cur3 + 1 == 3) ? 0 : cur3 + 1;

    // pv loads at loop top (single buffer; cover = full GEMM)
    f16x4 pv[4][2];
    if (P) {
#pragma unroll
      for (int ga = 0; ga < 4; ++ga)
#pragma unroll
        for (int s = 0; s < 2; ++s)
          pv[ga][s] = *(const f16x4*)(Pw + ((ga * 8 + s * 4 + w) * 64 + l) * 4);
    }
    f32x4 acc[4][2];
#pragma unroll
    for (int ga = 0; ga < 4; ++ga)
#pragma unroll
      for (int s = 0; s < 2; ++s) acc[ga][s] = f32x4{0.f, 0.f, 0.f, 0.f};

    const f16* hbc = hb[cur3];
    auto do_kt = [&](auto ktc, f16x8 hfrag) {
      constexpr int KT = decltype(ktc)::value;
#pragma unroll
      for (int ga = 0; ga < 4; ++ga)
#pragma unroll
        for (int s = 0; s < 2; ++s) {
          if constexpr (KT < 5) {
            acc[ga][s] = __builtin_amdgcn_mfma_f32_16x16x32_f16(wf[ga][s][KT], hfrag, acc[ga][s], 0, 0, 0);
          } else {
            int nl = ga * 128 + w * 32 + s * 16 + r;
            f16x8 aw = *(const f16x8*)&Wl[(nl * 96 + (KT - 5) * 32 + g * 8) ^ ((nl & 7) << 3)];
            acc[ga][s] = __builtin_amdgcn_mfma_f32_16x16x32_f16(aw, hfrag, acc[ga][s], 0, 0, 0);
          }
        }
    };
    auto ownfrag = [&](int ktl) {
      return *(const f16x8*)&hbc[(r * 128 + ktl * 32 + g * 8) ^ ((r & 7) << 3)];
    };

    // Own k-tile 0, then spin + CP-routed pa loads, then own k-tiles 1..3
    // (pa latency covered by ~350cy of MFMA).
    if (jh == 0) do_kt(ic<0>{}, ownfrag(0));
    else         do_kt(ic<4>{}, ownfrag(0));

    if (tl > 0) {
      spin_flag(&flags[pwg], (unsigned)v);
      const f16* HxR = Hx + ((size_t)(v & 1) * 16 + pwg) * 2048;
#pragma unroll
      for (int kt = 0; kt < 4; ++kt)
        pa[kt] = aload16(HxR + r * 128 + kt * 32 + g * 8);
    }

    if (jh == 0) { do_kt(ic<1>{}, ownfrag(1)); do_kt(ic<2>{}, ownfrag(2)); do_kt(ic<3>{}, ownfrag(3)); }
    else         { do_kt(ic<5>{}, ownfrag(1)); do_kt(ic<6>{}, ownfrag(2)); do_kt(ic<7>{}, ownfrag(3)); }

    // Partner-half k-tiles
    if (jh == 0) {
      do_kt(ic<4>{}, pa[0]); do_kt(ic<5>{}, pa[1]);
      do_kt(ic<6>{}, pa[2]); do_kt(ic<7>{}, pa[3]);
    } else {
      do_kt(ic<0>{}, pa[0]); do_kt(ic<1>{}, pa[1]);
      do_kt(ic<2>{}, pa[2]); do_kt(ic<3>{}, pa[3]);
    }

    // Elementwise -> h(v+1) own half; exchange store pre-barrier.
    f16* hbn = hb[nxt3];
    f16* HxW = Hx + ((size_t)((v + 1) & 1) * 16 + wg) * 2048;
#pragma unroll
    for (int s = 0; s < 2; ++s) {
      int j4 = w * 32 + s * 16 + 4 * g;
      float cold[4];
#pragma unroll
      for (int e = 0; e < 4; ++e) cold[e] = cb[(j4 + e) * 20 + r];
      f16x4 b4[4];
      if (!P) {
#pragma unroll
        for (int ga = 0; ga < 4; ++ga) b4[ga] = *(const f16x4*)&bl[ga * 128 + j4];
      }
      union { unsigned long long u; f16 h4[4]; } pk;
#pragma unroll
      for (int e = 0; e < 4; ++e) {
        float xi = acc[0][s][e], xf = acc[1][s][e], xg = acc[2][s][e], xo = acc[3][s][e];
        if (P) {
          xi += (float)pv[0][s][e]; xf += (float)pv[1][s][e];
          xg += (float)pv[2][s][e]; xo += (float)pv[3][s][e];
        } else {
          xi += (float)b4[0][e]; xf += (float)b4[1][e];
          xg += (float)b4[2][e]; xo += (float)b4[3][e];
        }
        float ii = sigm_(xi), ff = sigm_(xf), oo = sigm_(xo), gg = tanh_(xg);
        float cn = ff * cold[e] + ii * gg;
        cb[(j4 + e) * 20 + r] = cn;
        pk.h4[e] = (f16)(oo * tanh_(cn));
      }
      __hip_atomic_store((unsigned long long*)(HxW + r * 128 + j4), pk.u,
                         __ATOMIC_RELAXED, __HIP_MEMORY_SCOPE_AGENT);
      *(unsigned long long*)&hbn[(r * 128 + j4) ^ ((r & 7) << 3)] = pk.u;
    }
    __syncthreads();   // drains Hx atomics (vmcnt) + hbn visible to all

    if (tid == 0)
      __hip_atomic_store(&flags[wg], (unsigned)(v + 1),
                         __ATOMIC_RELEASE, __HIP_MEMORY_SCOPE_AGENT);

    // FUSED DECODE of h(v) -> out[t = v-1], in post-flag slack.
    if (v > 0) {
      f32x4 dacc = {0.f, 0.f, 0.f, 0.f};
#pragma unroll
      for (int i = 0; i < 4; ++i) {
        f16x8 hf = ownfrag(i);
        int ktg = jh * 4 + i;
        f16x8 aw = *(const f16x8*)&Wd[(o32 * 256 + ktg * 32 + g * 8) ^ ((o32 & 7) << 3)];
        dacc = __builtin_amdgcn_mfma_f32_16x16x32_f16(aw, hf, dacc, 0, 0, 0);
      }
#pragma unroll
      for (int i = 0; i < 4; ++i) {
        int ktg = (jh ^ 1) * 4 + i;
        f16x8 aw = *(const f16x8*)&Wd[(o32 * 256 + ktg * 32 + g * 8) ^ ((o32 & 7) << 3)];
        dacc = __builtin_amdgcn_mfma_f32_16x16x32_f16(aw, pa[i], dacc, 0, 0, 0);
      }
      if (w < 2) {
        f32x4 ov;
#pragma unroll
        for (int e = 0; e < 4; ++e) ov[e] = dacc[e] + dbias[e];
        *(f32x4*)(out + ((size_t)(b0 + r) * TT + (v - 1)) * OUTF + jh * 32 + (w & 1) * 16 + 4 * g) = ov;
      }
    }

    cur3 = nxt3;
    if (P) Pw += pstep;
  }

  // Tail decode (last chunk only): out[t = seq0+Tc-1] from h(seq0+Tc)
  if (do_tail) {
    spin_flag(&flags[pwg], (unsigned)(seq0 + Tc));
    const f16* HxR = Hx + ((size_t)((seq0 + Tc) & 1) * 16 + pwg) * 2048;
    f16x8 paT[4];
#pragma unroll
    for (int kt = 0; kt < 4; ++kt)
      paT[kt] = aload16(HxR + r * 128 + kt * 32 + g * 8);
    const f16* hbf = hb[cur3];
    f32x4 dacc = {0.f, 0.f, 0.f, 0.f};
#pragma unroll
    for (int i = 0; i < 4; ++i) {
      f16x8 hf = *(const f16x8*)&hbf[(r * 128 + i * 32 + g * 8) ^ ((r & 7) << 3)];
      int ktg = jh * 4 + i;
      f16x8 aw = *(const f16x8*)&Wd[(o32 * 256 + ktg * 32 + g * 8) ^ ((o32 & 7) << 3)];
      dacc = __builtin_amdgcn_mfma_f32_16x16x32_f16(aw, hf, dacc, 0, 0, 0);
    }
#pragma unroll
    for (int i = 0; i < 4; ++i) {
      int ktg = (jh ^ 1) * 4 + i;
      f16x8 aw = *(const f16x8*)&Wd[(o32 * 256 + ktg * 32 + g * 8) ^ ((o32 & 7) << 3)];
      dacc = __builtin_amdgcn_mfma_f32_16x16x32_f16(aw, paT[i], dacc, 0, 0, 0);
    }
    if (w < 2) {
      f32x4 ov;
#pragma unroll
      for (int e = 0; e < 4; ++e) ov[e] = dacc[e] + dbias[e];
      *(f32x4*)(out + ((size_t)(b0 + r) * TT + (seq0 + Tc - 1)) * OUTF + jh * 32 + (w & 1) * 16 + 4 * g) = ov;
    }
  }

  // persist own halves of state
  {
    const f16* hbf = hb[cur3];
    int b = tid >> 4, seg = tid & 15;
    f16x8 hv = *(const f16x8*)&hbf[(b * 128 + seg * 8) ^ ((b & 7) << 3)];
    *(f16x8*)(h_state + (size_t)(b0 + b) * HD + jh * 128 + seg * 8) = hv;
  }
  for (int i = tid; i < 16 * 128; i += 256) {
    int b = i >> 7, jl = i & 127;
    c_state[(size_t)(b0 + b) * HD + jh * 128 + jl] = cb[jl * 20 + b];
  }
}

// ---------------------------------------------------------------------------
extern "C" void kernel_launch(void* const* d_in, const int* in_sizes, int n_in,
                              void* d_out, int out_size, void* d_ws, size_t ws_size,
                              hipStream_t stream)
{
  const float* x     = (const float*)d_in[0];
  // d_in[1] = future_n (constant 512)
  const float* enc_W = (const float*)d_in[2];
  const float* enc_b = (const float*)d_in[3];
  const float* fut_W = (const float*)d_in[4];
  const float* fut_b = (const float*)d_in[5];
  const float* dec_W = (const float*)d_in[6];
  const float* dec_b = (const float*)d_in[7];
  const float* pW_ih = (const float*)d_in[8];
  const float* pW_hh = (const float*)d_in[9];
  const float* pb_ih = (const float*)d_in[10];
  const float* pb_hh = (const float*)d_in[11];
  const float* fW_ih = (const float*)d_in[12];
  const float* fW_hh = (const float*)d_in[13];
  const float* fb_ih = (const float*)d_in[14];
  const float* fb_hh = (const float*)d_in[15];
  (void)in_sizes; (void)n_in; (void)out_size;

  char* p = (char*)d_ws;
  auto alloc = [&](size_t bytes) { char* q = p; p += (bytes + 255) & ~(size_t)255; return q; };
  f16*   Wp_in = (f16*)  alloc((size_t)NG * INF * 2);
  float* bp    = (float*)alloc((size_t)NG * 4);
  f16*   Wp16  = (f16*)  alloc((size_t)NG * HD * 2);
  f16*   Wf16  = (f16*)  alloc((size_t)NG * HD * 2);
  float* bfb   = (float*)alloc((size_t)NG * 4);
  f16*   dW16  = (f16*)  alloc((size_t)OUTF * HD * 2);
  f16*   h_st  = (f16*)  alloc((size_t)B_ * HD * 2);
  float* c_st  = (float*)alloc((size_t)B_ * HD * 4);
  f16*   Hx    = (f16*)  alloc((size_t)2 * 16 * 2048 * 2);   // exchange, 128 KB
  unsigned int* flags = (unsigned int*)alloc(64);
  size_t fixed = (size_t)(p - (char*)d_ws);

  auto need = [&](int rr) {
    size_t pp = (size_t)(rr < TPAST ? rr : TPAST) * NG * B_ * 2;
    return pp + 4096;
  };
  size_t avail = ws_size > fixed ? ws_size - fixed : 0;
  int R = 128;
  if (avail >= need(1536)) R = 1536;
  else if (avail >= need(512)) R = 512;
  else if (avail >= need(256)) R = 256;

  f16* Pbuf = (f16*)alloc((size_t)(R < TPAST ? R : TPAST) * NG * B_ * 2);
  float* out = (float*)d_out;

  hipMemsetAsync(flags, 0, 64, stream);   // reset exchange flags each launch

  eprep<<<512, 256, 0, stream>>>(enc_W, enc_b, fut_W, fut_b, dec_W,
                                 pW_ih, pW_hh, pb_ih, pb_hh,
                                 fW_ih, fW_hh, fb_ih, fb_hh,
                                 Wp_in, bp, Wp16, Wf16, bfb, dW16);

  // past phase (decoder fused into erecur)
  for (int t0 = 0; t0 < TPAST; t0 += R) {
    int Tc = (TPAST - t0) < R ? (TPAST - t0) : R;
    epgemm<<<Tc * 8, 64, 0, stream>>>(x, Wp_in, bp, Pbuf, t0, Tc);
    erecur<<<16, 256, 0, stream>>>(Wp16, Pbuf, 8192, nullptr, dW16, dec_b, out,
                                   h_st, c_st, Hx, flags, Tc, t0, t0 == 0 ? 1 : 0, 0);
  }
  // future phase (encoder folded into Wf16; bias staged to LDS in-kernel)
  for (int t0 = TPAST; t0 < TT; t0 += R) {
    int Tc = (TT - t0) < R ? (TT - t0) : R;
    int tail = (t0 + Tc == TT) ? 1 : 0;
    erecur<<<16, 256, 0, stream>>>(Wf16, nullptr, 0, bfb, dW16, dec_b, out,
                                   h_st, c_st, Hx, flags, Tc, t0, 0, tail);
  }
}

// Round 23
// 5643.832 us; speedup vs baseline: 1.0610x; 1.0610x over previous
//
#include <hip/hip_runtime.h>

#define B_    128
#define TPAST 1024
#define FN    512
#define TT    1536
#define INF   64
#define IPF   128
#define HD    256
#define NG    1024
#define OUTF  64

typedef _Float16 f16;
typedef _Float16 f16x8 __attribute__((ext_vector_type(8)));
typedef _Float16 f16x4 __attribute__((ext_vector_type(4)));
typedef float    f32x4 __attribute__((ext_vector_type(4)));

template<int N> struct ic { static constexpr int value = N; };

__device__ __forceinline__ float sigm_(float x) {
  return __builtin_amdgcn_rcpf(1.f + __expf(-x));
}
__device__ __forceinline__ float tanh_(float x) {
  return 1.f - 2.f * __builtin_amdgcn_rcpf(1.f + __expf(2.f * x));
}
// Opaque 16B load (asm result can't be rematerialized -> stays resident).
__device__ __forceinline__ f16x8 oload16(const f16* p) {
  f16x8 v;
  asm volatile("global_load_dwordx4 %0, %1, off\n\ts_waitcnt vmcnt(0)"
               : "=v"(v) : "v"(p));
  return v;
}
// Spin on a partner flag with RELAXED loads (no per-poll cache invalidation),
// then ONE acquire fence before reading the exchanged data. Triple-confirmed
// (r17/r18/r20): any extra agent-scope coherence op per step flushes the XCD
// L2; this minimal form (1 release + relaxed poll + 1 acquire per step) is
// the only fast one. r22 also falsified replacing the fence with CP-routed
// atomic data reads (8 serialized CP loads cost more than the fence).
__device__ __forceinline__ void spin_flag(const unsigned int* f, unsigned tgt) {
  while (__hip_atomic_load(f, __ATOMIC_RELAXED, __HIP_MEMORY_SCOPE_AGENT) < tgt)
    __builtin_amdgcn_s_sleep(1);
  __builtin_amdgcn_fence(__ATOMIC_ACQUIRE, "agent");
}

// ---------------------------------------------------------------------------
// prep: fold encoder into past-input weights; fold future encoder into the
// future recurrent matrix; f16 weights.
// ---------------------------------------------------------------------------
extern "C" __global__ void eprep(
    const float* __restrict__ enc_W, const float* __restrict__ enc_b,
    const float* __restrict__ fut_W, const float* __restrict__ fut_b,
    const float* __restrict__ dec_W,
    const float* __restrict__ pW_ih, const float* __restrict__ pW_hh,
    const float* __restrict__ pb_ih, const float* __restrict__ pb_hh,
    const float* __restrict__ fW_ih, const float* __restrict__ fW_hh,
    const float* __restrict__ fb_ih, const float* __restrict__ fb_hh,
    f16* __restrict__ Wp_in, float* __restrict__ bp,
    f16* __restrict__ Wp16, f16* __restrict__ Wf16,
    float* __restrict__ bf, f16* __restrict__ dW16)
{
  int stride = gridDim.x * blockDim.x;
  int gid = blockIdx.x * blockDim.x + threadIdx.x;
  for (int i = gid; i < NG * HD; i += stride) {
    int n = i >> 8, j = i & 255;
    float s = fW_hh[i];
    for (int m = 0; m < IPF; ++m) s += fW_ih[n * IPF + m] * fut_W[m * HD + j];
    Wf16[i] = (f16)s;
    Wp16[i] = (f16)pW_hh[i];
  }
  for (int i = gid; i < NG * INF; i += stride) {
    int n = i >> 6, k = i & 63;
    float s = 0.f;
    for (int m = 0; m < IPF; ++m) s += pW_ih[n * IPF + m] * enc_W[m * INF + k];
    Wp_in[i] = (f16)s;
  }
  for (int i = gid; i < OUTF * HD; i += stride) dW16[i] = (f16)dec_W[i];
  for (int n = gid; n < NG; n += stride) {
    float s1 = pb_ih[n] + pb_hh[n], s2 = fb_ih[n] + fb_hh[n];
    for (int m = 0; m < IPF; ++m) {
      s1 += pW_ih[n * IPF + m] * enc_b[m];
      s2 += fW_ih[n * IPF + m] * fut_b[m];
    }
    bp[n] = s1; bf[n] = s2;
  }
}

// ---------------------------------------------------------------------------
// P GEMM, fragment-ordered "Q" layout (refcheck-passed, plain cached stores).
// ---------------------------------------------------------------------------
extern "C" __global__ __launch_bounds__(64) void epgemm(
    const float* __restrict__ x, const f16* __restrict__ Wp_in,
    const float* __restrict__ bp, f16* __restrict__ P, int t0, int Tc)
{
  int wg = blockIdx.x;
  int tl = wg >> 3, bt = wg & 7;
  int t = t0 + tl;
  int l = (int)threadIdx.x, r = l & 15, g = l >> 4;
  const float* xb = x + ((size_t)(bt * 16 + r) * TPAST + t) * INF;
  f16x8 a[2];
#pragma unroll
  for (int kk = 0; kk < 2; ++kk) {
    const float* px = xb + kk * 32 + g * 8;
    f32x4 v0 = *(const f32x4*)px;
    f32x4 v1 = *(const f32x4*)(px + 4);
#pragma unroll
    for (int e = 0; e < 4; ++e) { a[kk][e] = (f16)v0[e]; a[kk][4 + e] = (f16)v1[e]; }
  }
  for (int nt = 0; nt < 64; ++nt) {
    int n = nt * 16 + r;
    f16x8 w0 = *(const f16x8*)(Wp_in + (size_t)n * INF + g * 8);
    f16x8 w1 = *(const f16x8*)(Wp_in + (size_t)n * INF + 32 + g * 8);
    f32x4 acc = {0.f, 0.f, 0.f, 0.f};
    acc = __builtin_amdgcn_mfma_f32_16x16x32_f16(w0, a[0], acc, 0, 0, 0);
    acc = __builtin_amdgcn_mfma_f32_16x16x32_f16(w1, a[1], acc, 0, 0, 0);
    f32x4 bias4 = *(const f32x4*)&bp[nt * 16 + 4 * g];
    f16x4 hv;
#pragma unroll
    for (int e = 0; e < 4; ++e) hv[e] = (f16)(acc[e] + bias4[e]);
    int ga = nt >> 4, jhp = (nt >> 3) & 1, wc = (nt >> 1) & 3, sc = nt & 1;
    f16* Pt = P + ((size_t)(jhp * 8 + bt) * Tc + tl) * 8192;
    *(f16x4*)(Pt + ((ga * 8 + sc * 4 + wc) * 64 + l) * 4) = hv;
  }
}

// ---------------------------------------------------------------------------
// Persistent recurrent kernel (r21, best measured 5.66 ms): C^T orientation,
// 16 WGs x 256 threads, same-XCD pairing, weights resident (160 VGPR + 96KB
// LDS), fused decoder in post-flag slack, tri-buffered hb, pa-cover reorder
// (own-kt0 -> spin -> pa loads -> own-kt1..3 -> partner kts), minimal
// coherence protocol.
// ---------------------------------------------------------------------------
extern "C" __global__ __launch_bounds__(256, 1)
void erecur(
    const f16* __restrict__ W, const f16* __restrict__ P, int pstep,
    const float* __restrict__ bias,
    const f16* __restrict__ dW, const float* __restrict__ dec_b,
    float* __restrict__ out,
    f16* __restrict__ h_state, float* __restrict__ c_state,
    f16* __restrict__ Hx, unsigned int* __restrict__ flags,
    int Tc, int seq0, int init_state, int do_tail)
{
  __shared__ f16  Wl[512 * 96];     //  96 KB : W rows (this WG), cols 160..255
  __shared__ f16  Wd[32 * 256];     //  16 KB : decoder rows jh*32..+32, swizzled
  __shared__ f16  hb[3][16 * 128];  //  12 KB : own h half, TRI-buffered, swizzled
  __shared__ float cb[128 * 20];    //  10 KB : own c [jl][b], stride 20
  __shared__ f16  bl[512];          //   1 KB : future bias (own rows)

  int tid = (int)threadIdx.x;
  int w = tid >> 6, l = tid & 63, r = l & 15, g = l >> 4;
  int wg = blockIdx.x;
  int bs = wg & 7, jh = wg >> 3;
  int b0 = bs * 16;
  int pwg = wg ^ 8;

  for (int nl = tid; nl < 512; nl += 256) {
    int ng = (nl >> 7) * 256 + jh * 128 + (nl & 127);
#pragma unroll
    for (int c8 = 0; c8 < 12; ++c8) {
      f16x8 v = *(const f16x8*)(W + (size_t)ng * HD + 160 + c8 * 8);
      *(f16x8*)&Wl[(nl * 96 + c8 * 8) ^ ((nl & 7) << 3)] = v;
    }
  }
  // Decoder weight slice for this jh (rows jh*32 .. jh*32+32), swizzled
  for (int i = tid; i < 32 * 32; i += 256) {
    int row = i >> 5, c8 = i & 31;
    f16x8 v = *(const f16x8*)(dW + (size_t)(jh * 32 + row) * HD + c8 * 8);
    *(f16x8*)&Wd[(row * 256 + c8 * 8) ^ ((row & 7) << 3)] = v;
  }
  if (bias) {
    for (int i = tid; i < 512; i += 256) {
      int ng = (i >> 7) * 256 + jh * 128 + (i & 127);
      bl[i] = (f16)bias[ng];
    }
  }
  f16x8 wf[4][2][5];
#pragma unroll
  for (int ga = 0; ga < 4; ++ga)
#pragma unroll
    for (int s = 0; s < 2; ++s) {
      int ng = ga * 256 + jh * 128 + w * 32 + s * 16 + r;
#pragma unroll
      for (int kt = 0; kt < 5; ++kt)
        wf[ga][s][kt] = oload16(W + (size_t)ng * HD + kt * 32 + g * 8);
    }
  f32x4 dbias = *(const f32x4*)(dec_b + jh * 32 + (w & 1) * 16 + 4 * g);
  int o32 = (w & 1) * 16 + r;

  int cur3 = seq0 % 3;
  f16x8 pa[4];
  if (init_state) {
    for (int i = tid; i < 16 * 128; i += 256) {
      int b = i >> 7, jl = i & 127;
      hb[cur3][(b * 128 + jl) ^ ((b & 7) << 3)] = (f16)0.f;
    }
    for (int i = tid; i < 128 * 20; i += 256) cb[i] = 0.f;
    f16x8 z = {};
#pragma unroll
    for (int kt = 0; kt < 4; ++kt) pa[kt] = z;
  } else {
    for (int i = tid; i < 16 * 128; i += 256) {
      int b = i >> 7, jl = i & 127;
      hb[cur3][(b * 128 + jl) ^ ((b & 7) << 3)] =
          h_state[(size_t)(b0 + b) * HD + jh * 128 + jl];
    }
    for (int i = tid; i < 16 * 128; i += 256) {
      int b = i >> 7, jl = i & 127;
      cb[jl * 20 + b] = c_state[(size_t)(b0 + b) * HD + jh * 128 + jl];
    }
#pragma unroll
    for (int kt = 0; kt < 4; ++kt)
      pa[kt] = *(const f16x8*)(h_state + (size_t)(b0 + r) * HD + (jh ^ 1) * 128 + kt * 32 + g * 8);
  }
  const f16* Pw = P ? (P + (size_t)wg * Tc * pstep) : nullptr;
  __syncthreads();

  for (int tl = 0; tl < Tc; ++tl) {
    int v = seq0 + tl;
    int nxt3 = (cur3 + 1 == 3) ? 0 : cur3 + 1;

    // pv loads at loop top (single buffer; cover = full GEMM)
    f16x4 pv[4][2];
    if (P) {
#pragma unroll
      for (int ga = 0; ga < 4; ++ga)
#pragma unroll
        for (int s = 0; s < 2; ++s)
          pv[ga][s] = *(const f16x4*)(Pw + ((ga * 8 + s * 4 + w) * 64 + l) * 4);
    }
    f32x4 acc[4][2];
#pragma unroll
    for (int ga = 0; ga < 4; ++ga)
#pragma unroll
      for (int s = 0; s < 2; ++s) acc[ga][s] = f32x4{0.f, 0.f, 0.f, 0.f};

    const f16* hbc = hb[cur3];
    auto do_kt = [&](auto ktc, f16x8 hfrag) {
      constexpr int KT = decltype(ktc)::value;
#pragma unroll
      for (int ga = 0; ga < 4; ++ga)
#pragma unroll
        for (int s = 0; s < 2; ++s) {
          if constexpr (KT < 5) {
            acc[ga][s] = __builtin_amdgcn_mfma_f32_16x16x32_f16(wf[ga][s][KT], hfrag, acc[ga][s], 0, 0, 0);
          } else {
            int nl = ga * 128 + w * 32 + s * 16 + r;
            f16x8 aw = *(const f16x8*)&Wl[(nl * 96 + (KT - 5) * 32 + g * 8) ^ ((nl & 7) << 3)];
            acc[ga][s] = __builtin_amdgcn_mfma_f32_16x16x32_f16(aw, hfrag, acc[ga][s], 0, 0, 0);
          }
        }
    };
    auto ownfrag = [&](int ktl) {
      return *(const f16x8*)&hbc[(r * 128 + ktl * 32 + g * 8) ^ ((r & 7) << 3)];
    };

    // Own k-tile 0, then spin + pa loads, then own k-tiles 1..3 so the pa
    // round-trip is covered by ~350cy of MFMA instead of fully exposed.
    if (jh == 0) do_kt(ic<0>{}, ownfrag(0));
    else         do_kt(ic<4>{}, ownfrag(0));

    if (tl > 0) {
      spin_flag(&flags[pwg], (unsigned)v);
      const f16* HxR = Hx + ((size_t)(v & 1) * 16 + pwg) * 2048;
#pragma unroll
      for (int kt = 0; kt < 4; ++kt)
        pa[kt] = *(const f16x8*)(HxR + r * 128 + kt * 32 + g * 8);
    }

    if (jh == 0) { do_kt(ic<1>{}, ownfrag(1)); do_kt(ic<2>{}, ownfrag(2)); do_kt(ic<3>{}, ownfrag(3)); }
    else         { do_kt(ic<5>{}, ownfrag(1)); do_kt(ic<6>{}, ownfrag(2)); do_kt(ic<7>{}, ownfrag(3)); }

    // Partner-half k-tiles
    if (jh == 0) {
      do_kt(ic<4>{}, pa[0]); do_kt(ic<5>{}, pa[1]);
      do_kt(ic<6>{}, pa[2]); do_kt(ic<7>{}, pa[3]);
    } else {
      do_kt(ic<0>{}, pa[0]); do_kt(ic<1>{}, pa[1]);
      do_kt(ic<2>{}, pa[2]); do_kt(ic<3>{}, pa[3]);
    }

    // Elementwise -> h(v+1) own half; exchange store pre-barrier.
    f16* hbn = hb[nxt3];
    f16* HxW = Hx + ((size_t)((v + 1) & 1) * 16 + wg) * 2048;
#pragma unroll
    for (int s = 0; s < 2; ++s) {
      int j4 = w * 32 + s * 16 + 4 * g;
      float cold[4];
#pragma unroll
      for (int e = 0; e < 4; ++e) cold[e] = cb[(j4 + e) * 20 + r];
      f16x4 b4[4];
      if (!P) {
#pragma unroll
        for (int ga = 0; ga < 4; ++ga) b4[ga] = *(const f16x4*)&bl[ga * 128 + j4];
      }
      union { unsigned long long u; f16 h4[4]; } pk;
#pragma unroll
      for (int e = 0; e < 4; ++e) {
        float xi = acc[0][s][e], xf = acc[1][s][e], xg = acc[2][s][e], xo = acc[3][s][e];
        if (P) {
          xi += (float)pv[0][s][e]; xf += (float)pv[1][s][e];
          xg += (float)pv[2][s][e]; xo += (float)pv[3][s][e];
        } else {
          xi += (float)b4[0][e]; xf += (float)b4[1][e];
          xg += (float)b4[2][e]; xo += (float)b4[3][e];
        }
        float ii = sigm_(xi), ff = sigm_(xf), oo = sigm_(xo), gg = tanh_(xg);
        float cn = ff * cold[e] + ii * gg;
        cb[(j4 + e) * 20 + r] = cn;
        pk.h4[e] = (f16)(oo * tanh_(cn));
      }
      __hip_atomic_store((unsigned long long*)(HxW + r * 128 + j4), pk.u,
                         __ATOMIC_RELAXED, __HIP_MEMORY_SCOPE_AGENT);
      *(unsigned long long*)&hbn[(r * 128 + j4) ^ ((r & 7) << 3)] = pk.u;
    }
    __syncthreads();   // drains Hx atomics (vmcnt) + hbn visible to all

    if (tid == 0)
      __hip_atomic_store(&flags[wg], (unsigned)(v + 1),
                         __ATOMIC_RELEASE, __HIP_MEMORY_SCOPE_AGENT);

    // FUSED DECODE of h(v) -> out[t = v-1], in post-flag slack.
    if (v > 0) {
      f32x4 dacc = {0.f, 0.f, 0.f, 0.f};
#pragma unroll
      for (int i = 0; i < 4; ++i) {
        f16x8 hf = ownfrag(i);
        int ktg = jh * 4 + i;
        f16x8 aw = *(const f16x8*)&Wd[(o32 * 256 + ktg * 32 + g * 8) ^ ((o32 & 7) << 3)];
        dacc = __builtin_amdgcn_mfma_f32_16x16x32_f16(aw, hf, dacc, 0, 0, 0);
      }
#pragma unroll
      for (int i = 0; i < 4; ++i) {
        int ktg = (jh ^ 1) * 4 + i;
        f16x8 aw = *(const f16x8*)&Wd[(o32 * 256 + ktg * 32 + g * 8) ^ ((o32 & 7) << 3)];
        dacc = __builtin_amdgcn_mfma_f32_16x16x32_f16(aw, pa[i], dacc, 0, 0, 0);
      }
      if (w < 2) {
        f32x4 ov;
#pragma unroll
        for (int e = 0; e < 4; ++e) ov[e] = dacc[e] + dbias[e];
        *(f32x4*)(out + ((size_t)(b0 + r) * TT + (v - 1)) * OUTF + jh * 32 + (w & 1) * 16 + 4 * g) = ov;
      }
    }

    cur3 = nxt3;
    if (P) Pw += pstep;
  }

  // Tail decode (last chunk only): out[t = seq0+Tc-1] from h(seq0+Tc)
  if (do_tail) {
    spin_flag(&flags[pwg], (unsigned)(seq0 + Tc));
    const f16* HxR = Hx + ((size_t)((seq0 + Tc) & 1) * 16 + pwg) * 2048;
    f16x8 paT[4];
#pragma unroll
    for (int kt = 0; kt < 4; ++kt)
      paT[kt] = *(const f16x8*)(HxR + r * 128 + kt * 32 + g * 8);
    const f16* hbf = hb[cur3];
    f32x4 dacc = {0.f, 0.f, 0.f, 0.f};
#pragma unroll
    for (int i = 0; i < 4; ++i) {
      f16x8 hf = *(const f16x8*)&hbf[(r * 128 + i * 32 + g * 8) ^ ((r & 7) << 3)];
      int ktg = jh * 4 + i;
      f16x8 aw = *(const f16x8*)&Wd[(o32 * 256 + ktg * 32 + g * 8) ^ ((o32 & 7) << 3)];
      dacc = __builtin_amdgcn_mfma_f32_16x16x32_f16(aw, hf, dacc, 0, 0, 0);
    }
#pragma unroll
    for (int i = 0; i < 4; ++i) {
      int ktg = (jh ^ 1) * 4 + i;
      f16x8 aw = *(const f16x8*)&Wd[(o32 * 256 + ktg * 32 + g * 8) ^ ((o32 & 7) << 3)];
      dacc = __builtin_amdgcn_mfma_f32_16x16x32_f16(aw, paT[i], dacc, 0, 0, 0);
    }
    if (w < 2) {
      f32x4 ov;
#pragma unroll
      for (int e = 0; e < 4; ++e) ov[e] = dacc[e] + dbias[e];
      *(f32x4*)(out + ((size_t)(b0 + r) * TT + (seq0 + Tc - 1)) * OUTF + jh * 32 + (w & 1) * 16 + 4 * g) = ov;
    }
  }

  // persist own halves of state
  {
    const f16* hbf = hb[cur3];
    int b = tid >> 4, seg = tid & 15;
    f16x8 hv = *(const f16x8*)&hbf[(b * 128 + seg * 8) ^ ((b & 7) << 3)];
    *(f16x8*)(h_state + (size_t)(b0 + b) * HD + jh * 128 + seg * 8) = hv;
  }
  for (int i = tid; i < 16 * 128; i += 256) {
    int b = i >> 7, jl = i & 127;
    c_state[(size_t)(b0 + b) * HD + jh * 128 + jl] = cb[jl * 20 + b];
  }
}

// ---------------------------------------------------------------------------
extern "C" void kernel_launch(void* const* d_in, const int* in_sizes, int n_in,
                              void* d_out, int out_size, void* d_ws, size_t ws_size,
                              hipStream_t stream)
{
  const float* x     = (const float*)d_in[0];
  // d_in[1] = future_n (constant 512)
  const float* enc_W = (const float*)d_in[2];
  const float* enc_b = (const float*)d_in[3];
  const float* fut_W = (const float*)d_in[4];
  const float* fut_b = (const float*)d_in[5];
  const float* dec_W = (const float*)d_in[6];
  const float* dec_b = (const float*)d_in[7];
  const float* pW_ih = (const float*)d_in[8];
  const float* pW_hh = (const float*)d_in[9];
  const float* pb_ih = (const float*)d_in[10];
  const float* pb_hh = (const float*)d_in[11];
  const float* fW_ih = (const float*)d_in[12];
  const float* fW_hh = (const float*)d_in[13];
  const float* fb_ih = (const float*)d_in[14];
  const float* fb_hh = (const float*)d_in[15];
  (void)in_sizes; (void)n_in; (void)out_size;

  char* p = (char*)d_ws;
  auto alloc = [&](size_t bytes) { char* q = p; p += (bytes + 255) & ~(size_t)255; return q; };
  f16*   Wp_in = (f16*)  alloc((size_t)NG * INF * 2);
  float* bp    = (float*)alloc((size_t)NG * 4);
  f16*   Wp16  = (f16*)  alloc((size_t)NG * HD * 2);
  f16*   Wf16  = (f16*)  alloc((size_t)NG * HD * 2);
  float* bfb   = (float*)alloc((size_t)NG * 4);
  f16*   dW16  = (f16*)  alloc((size_t)OUTF * HD * 2);
  f16*   h_st  = (f16*)  alloc((size_t)B_ * HD * 2);
  float* c_st  = (float*)alloc((size_t)B_ * HD * 4);
  f16*   Hx    = (f16*)  alloc((size_t)2 * 16 * 2048 * 2);   // exchange, 128 KB
  unsigned int* flags = (unsigned int*)alloc(64);
  size_t fixed = (size_t)(p - (char*)d_ws);

  auto need = [&](int rr) {
    size_t pp = (size_t)(rr < TPAST ? rr : TPAST) * NG * B_ * 2;
    return pp + 4096;
  };
  size_t avail = ws_size > fixed ? ws_size - fixed : 0;
  int R = 128;
  if (avail >= need(1536)) R = 1536;
  else if (avail >= need(512)) R = 512;
  else if (avail >= need(256)) R = 256;

  f16* Pbuf = (f16*)alloc((size_t)(R < TPAST ? R : TPAST) * NG * B_ * 2);
  float* out = (float*)d_out;

  hipMemsetAsync(flags, 0, 64, stream);   // reset exchange flags each launch

  eprep<<<512, 256, 0, stream>>>(enc_W, enc_b, fut_W, fut_b, dec_W,
                                 pW_ih, pW_hh, pb_ih, pb_hh,
                                 fW_ih, fW_hh, fb_ih, fb_hh,
                                 Wp_in, bp, Wp16, Wf16, bfb, dW16);

  // past phase (decoder fused into erecur)
  for (int t0 = 0; t0 < TPAST; t0 += R) {
    int Tc = (TPAST - t0) < R ? (TPAST - t0) : R;
    epgemm<<<Tc * 8, 64, 0, stream>>>(x, Wp_in, bp, Pbuf, t0, Tc);
    erecur<<<16, 256, 0, stream>>>(Wp16, Pbuf, 8192, nullptr, dW16, dec_b, out,
                                   h_st, c_st, Hx, flags, Tc, t0, t0 == 0 ? 1 : 0, 0);
  }
  // future phase (encoder folded into Wf16; bias staged to LDS in-kernel)
  for (int t0 = TPAST; t0 < TT; t0 += R) {
    int Tc = (TT - t0) < R ? (TT - t0) : R;
    int tail = (t0 + Tc == TT) ? 1 : 0;
    erecur<<<16, 256, 0, stream>>>(Wf16, nullptr, 0, bfb, dW16, dec_b, out,
                                   h_st, c_st, Hx, flags, Tc, t0, 0, tail);
  }
}